// Round 7
// baseline (6953.833 us; speedup 1.0000x reference)
//
#include <hip/hip_runtime.h>
#include <hip/hip_cooperative_groups.h>
#include <hip/hip_bf16.h>
#include <math.h>

namespace cg = cooperative_groups;

#define N_NODES 100000
#define N_EDGES 3200000
#define IN_DIM 512
#define HID 64
#define N_CLASSES 7
#define LAYERS 32
#define ALPHA 0.1f
#define THETA 0.5f

#define CDIV(a, b) (((a) + (b) - 1) / (b))

typedef unsigned int uint32;
typedef unsigned short ushort16;

// bf16 helpers (RNE pack, bit-shift unpack)
__device__ __forceinline__ ushort16 f2bf(float f) {
    union { float f; uint32 u; } x; x.f = f;
    uint32 r = x.u + 0x7FFFu + ((x.u >> 16) & 1u);
    return (ushort16)(r >> 16);
}
__device__ __forceinline__ float bflo(uint32 u) {
    union { uint32 u; float f; } x; x.u = u << 16; return x.f;
}
__device__ __forceinline__ float bfhi(uint32 u) {
    union { uint32 u; float f; } x; x.u = u & 0xFFFF0000u; return x.f;
}
__device__ __forceinline__ float bf2f(ushort16 s) {
    union { uint32 u; float f; } x; x.u = ((uint32)s) << 16; return x.f;
}

// ---------------- edge dtype detection (int32 vs int64 storage) ----------------
__global__ void k_detect(const unsigned int* __restrict__ ei, int* __restrict__ flag) {
    if (threadIdx.x == 0 && blockIdx.x == 0) {
        int is64 = 1;
        for (int i = 0; i < 16; i++)
            if (ei[2 * i + 1] != 0u) { is64 = 0; break; }
        *flag = is64;
    }
}

__device__ __forceinline__ int edge_elem(const int* ei, int is64, int idx) {
    return is64 ? ei[2 * (long long)idx] : ei[idx];
}

// ---------------- degree histogram ----------------
__global__ void k_zero_cnt(int* __restrict__ cnt) {
    int i = blockIdx.x * blockDim.x + threadIdx.x;
    if (i < N_NODES) cnt[i] = 0;
}

__global__ void k_count(const int* __restrict__ ei, const int* __restrict__ flag,
                        int* __restrict__ cnt) {
    int is64 = *flag;
    int e = blockIdx.x * blockDim.x + threadIdx.x;
    if (e >= N_EDGES) return;
    int d = edge_elem(ei, is64, N_EDGES + e);
    atomicAdd(&cnt[d], 1);
}

__global__ void k_dinv(const int* __restrict__ cnt, float* __restrict__ dinv) {
    int i = blockIdx.x * blockDim.x + threadIdx.x;
    if (i < N_NODES) dinv[i] = rsqrtf((float)(cnt[i] + 1));  // +1 self-loop
}

// ---------------- exclusive scan over cnt -> row_start ----------------
#define SCAN_T 256
#define SCAN_ELEMS 1024

__global__ void k_scan1(const int* __restrict__ cnt, int* __restrict__ rs,
                        int* __restrict__ bsum) {
    __shared__ int sh[SCAN_T];
    int t = threadIdx.x;
    int base = blockIdx.x * SCAN_ELEMS + t * 4;
    int v0 = (base + 0 < N_NODES) ? cnt[base + 0] : 0;
    int v1 = (base + 1 < N_NODES) ? cnt[base + 1] : 0;
    int v2 = (base + 2 < N_NODES) ? cnt[base + 2] : 0;
    int v3 = (base + 3 < N_NODES) ? cnt[base + 3] : 0;
    int ts = v0 + v1 + v2 + v3;
    sh[t] = ts;
    __syncthreads();
    for (int off = 1; off < SCAN_T; off <<= 1) {
        int x = 0;
        if (t >= off) x = sh[t - off];
        __syncthreads();
        if (t >= off) sh[t] += x;
        __syncthreads();
    }
    int excl = sh[t] - ts;
    if (t == SCAN_T - 1) bsum[blockIdx.x] = sh[t];
    int run = excl;
    if (base + 0 < N_NODES) rs[base + 0] = run; run += v0;
    if (base + 1 < N_NODES) rs[base + 1] = run; run += v1;
    if (base + 2 < N_NODES) rs[base + 2] = run; run += v2;
    if (base + 3 < N_NODES) rs[base + 3] = run;
}

__global__ void k_scan2(const int* __restrict__ bsum, int* __restrict__ bofs, int nb) {
    __shared__ int sh[256];
    int t = threadIdx.x;
    int v = (t < nb) ? bsum[t] : 0;
    sh[t] = v;
    __syncthreads();
    for (int off = 1; off < 256; off <<= 1) {
        int x = 0;
        if (t >= off) x = sh[t - off];
        __syncthreads();
        if (t >= off) sh[t] += x;
        __syncthreads();
    }
    if (t < nb) bofs[t] = sh[t] - v;
}

__global__ void k_scan3(int* __restrict__ rs, const int* __restrict__ bofs,
                        int* __restrict__ fill) {
    int i = blockIdx.x * blockDim.x + threadIdx.x;
    if (i < N_NODES) {
        rs[i] += bofs[i / SCAN_ELEMS];
        fill[i] = 0;
    }
    if (i == 0) rs[N_NODES] = N_EDGES;
}

// ---------------- CSR scatter (sorted by dst) ----------------
__global__ void k_scatter(const int* __restrict__ ei, const int* __restrict__ flag,
                          const int* __restrict__ rs, int* __restrict__ fill,
                          int* __restrict__ ssrc) {
    int is64 = *flag;
    int e = blockIdx.x * blockDim.x + threadIdx.x;
    if (e >= N_EDGES) return;
    int s = edge_elem(ei, is64, e);
    int d = edge_elem(ei, is64, N_EDGES + e);
    int pos = rs[d] + atomicAdd(&fill[d], 1);
    ssrc[pos] = s;
}

// ---------------- h0 = relu(x @ W0 + b0) [f32]; hs0 = dinv*h0 [bf16x2] ----------------
__global__ __launch_bounds__(256) void k_h0(const float* __restrict__ x,
                                            const float* __restrict__ W0,
                                            const float* __restrict__ b0,
                                            const float* __restrict__ dinv,
                                            float* __restrict__ h0,
                                            uint32* __restrict__ hs0) {
    __shared__ float xs[32][68];
    __shared__ float ws[32][68];
    int t = threadIdx.x;
    int row0 = blockIdx.x * 64;
    int tm = t >> 4, tn = t & 15;
    float acc[4][4] = {};

    for (int k0 = 0; k0 < IN_DIM; k0 += 32) {
        #pragma unroll
        for (int j = 0; j < 2; j++) {
            int lin = t + j * 256;
            int r = lin >> 3, c4 = lin & 7;
            int row = row0 + r;
            float4 v = make_float4(0.f, 0.f, 0.f, 0.f);
            if (row < N_NODES)
                v = *(const float4*)&x[(size_t)row * IN_DIM + k0 + c4 * 4];
            xs[c4 * 4 + 0][r] = v.x;
            xs[c4 * 4 + 1][r] = v.y;
            xs[c4 * 4 + 2][r] = v.z;
            xs[c4 * 4 + 3][r] = v.w;
        }
        #pragma unroll
        for (int j = 0; j < 2; j++) {
            int lin = t + j * 256;
            int kr = lin >> 4, c4 = lin & 15;
            *(float4*)&ws[kr][c4 * 4] = *(const float4*)&W0[(size_t)(k0 + kr) * HID + c4 * 4];
        }
        __syncthreads();
        #pragma unroll
        for (int kk = 0; kk < 32; kk++) {
            float4 av = *(const float4*)&xs[kk][tm * 4];
            float4 bv = *(const float4*)&ws[kk][tn * 4];
            float a4[4] = {av.x, av.y, av.z, av.w};
            float b4[4] = {bv.x, bv.y, bv.z, bv.w};
            #pragma unroll
            for (int i = 0; i < 4; i++)
                #pragma unroll
                for (int j = 0; j < 4; j++)
                    acc[i][j] = fmaf(a4[i], b4[j], acc[i][j]);
        }
        __syncthreads();
    }
    #pragma unroll
    for (int i = 0; i < 4; i++) {
        int row = row0 + tm * 4 + i;
        if (row < N_NODES) {
            float dn = dinv[row];
            float4 o;
            o.x = fmaxf(acc[i][0] + b0[tn * 4 + 0], 0.f);
            o.y = fmaxf(acc[i][1] + b0[tn * 4 + 1], 0.f);
            o.z = fmaxf(acc[i][2] + b0[tn * 4 + 2], 0.f);
            o.w = fmaxf(acc[i][3] + b0[tn * 4 + 3], 0.f);
            *(float4*)&h0[(size_t)row * HID + tn * 4] = o;
            uint32 p0 = (uint32)f2bf(o.x * dn) | ((uint32)f2bf(o.y * dn) << 16);
            uint32 p1 = (uint32)f2bf(o.z * dn) | ((uint32)f2bf(o.w * dn) << 16);
            uint2 pk; pk.x = p0; pk.y = p1;
            *(uint2*)&hs0[(size_t)row * 32 + tn * 2] = pk;
        }
    }
}

#define NODES_PER_BLOCK 32
#define LWAVES 4
#define EB 8  // 8 dual-row loads per window = 16 edges in flight

// ---------------- cooperative: ALL 32 layers in one dispatch ----------------
__global__ __launch_bounds__(256) void k_layers(
    uint32* __restrict__ hsA, uint32* __restrict__ hsB,
    const float* __restrict__ h0, const float* __restrict__ Wl,
    const int* __restrict__ rs, const int* __restrict__ ssrc,
    const float* __restrict__ dinv) {
    cg::grid_group grid = cg::this_grid();
    __shared__ float Ws[HID][HID + 1];
    __shared__ float ow[LWAVES][HID];
    int t = threadIdx.x;
    int w = t >> 6, lane = t & 63;
    int half = lane >> 5;   // 0: even edges, 1: odd edges
    int fl = lane & 31;     // feature-pair index
    int nblocks = gridDim.x;
    int chunk = (N_NODES + nblocks - 1) / nblocks;
    int nbeg = blockIdx.x * chunk;
    int nend = nbeg + chunk; if (nend > N_NODES) nend = N_NODES;

    const uint32* hin = hsA;
    uint32* hout = hsB;

    for (int l = 0; l < LAYERS; ++l) {
        float beta = logf(THETA / (float)(l + 1) + 1.0f);
        const float* W = Wl + (size_t)l * HID * HID;
        #pragma unroll
        for (int j = 0; j < 16; j++) {
            int lin = t + j * 256;
            Ws[lin >> 6][lin & 63] = W[lin];
        }
        __syncthreads();

        #pragma unroll 1
        for (int n = nbeg + w; n < nend; n += LWAVES) {
            float ax = 0.f, ay = 0.f;
            int e0 = rs[n], e1 = rs[n + 1];
            if (e1 > e0) {
                int sj[EB], sn[EB];
                #pragma unroll
                for (int j = 0; j < EB; j++)
                    sj[j] = ssrc[min(e0 + 2 * j + half, e1 - 1)];
                #pragma unroll 1
                for (int e = e0; e < e1; e += 2 * EB) {
                    uint32 uj[EB];
                    #pragma unroll
                    for (int j = 0; j < EB; j++) {
                        uint32 off = (uint32)sj[j] * 32u + (uint32)fl;
                        uj[j] = hin[off];
                    }
                    int en = e + 2 * EB;
                    // prefetch next window's indices while gathers are in flight
                    #pragma unroll
                    for (int j = 0; j < EB; j++)
                        sn[j] = ssrc[min(en + 2 * j + half, e1 - 1)];
                    #pragma unroll
                    for (int j = 0; j < EB; j++) {
                        if (e + 2 * j + half < e1) { ax += bflo(uj[j]); ay += bfhi(uj[j]); }
                    }
                    #pragma unroll
                    for (int j = 0; j < EB; j++) sj[j] = sn[j];
                }
            }
            ax += __shfl_xor(ax, 32);
            ay += __shfl_xor(ay, 32);
            uint32 su = hin[(uint32)n * 32u + fl];
            ax += bflo(su);
            ay += bfhi(su);
            float dn = dinv[n];
            float2 h0v = *(const float2*)&h0[(size_t)n * HID + fl * 2];
            float ox = 0.9f * (dn * ax) + 0.1f * h0v.x;
            float oy = 0.9f * (dn * ay) + 0.1f * h0v.y;
            if (lane < 32) *(float2*)&ow[w][fl * 2] = make_float2(ox, oy);
            __builtin_amdgcn_wave_barrier();
            float acc2 = 0.f;
            #pragma unroll
            for (int f = 0; f < HID; f += 4) {
                float4 o4 = *(const float4*)&ow[w][f];
                acc2 = fmaf(o4.x, Ws[f + 0][lane], acc2);
                acc2 = fmaf(o4.y, Ws[f + 1][lane], acc2);
                acc2 = fmaf(o4.z, Ws[f + 2][lane], acc2);
                acc2 = fmaf(o4.w, Ws[f + 3][lane], acc2);
            }
            float oself = ow[w][lane];
            __builtin_amdgcn_wave_barrier();
            float hn = beta * acc2 + (1.f - beta) * oself;
            ((ushort16*)hout)[(size_t)n * HID + lane] = f2bf(dn * fmaxf(hn, 0.f));
        }
        grid.sync();
        const uint32* tmp = hin; hin = hout; hout = (uint32*)tmp;
    }
}

// ---------------- classic per-layer kernel (fallback path) ----------------
__global__ __launch_bounds__(256) void k_layer(
    const uint32* __restrict__ hsin, const float* __restrict__ h0,
    ushort16* __restrict__ hsout, const float* __restrict__ W,
    const int* __restrict__ rs, const int* __restrict__ ssrc,
    const float* __restrict__ dinv, float beta) {
    __shared__ float Ws[HID][HID + 1];
    __shared__ float ow[LWAVES][HID];
    int t = threadIdx.x;
    #pragma unroll
    for (int j = 0; j < 16; j++) {
        int lin = t + j * 256;
        Ws[lin >> 6][lin & 63] = W[lin];
    }
    __syncthreads();

    int w = t >> 6, lane = t & 63;
    int half = lane >> 5;
    int fl = lane & 31;
    int nbase = blockIdx.x * NODES_PER_BLOCK + w * (NODES_PER_BLOCK / LWAVES);
    #pragma unroll 1
    for (int ni = 0; ni < NODES_PER_BLOCK / LWAVES; ni++) {
        int n = nbase + ni;
        float ax = 0.f, ay = 0.f;
        int e0 = rs[n], e1 = rs[n + 1];
        #pragma unroll 1
        for (int e = e0; e < e1; e += 2 * EB) {
            int sj[EB];
            uint32 uj[EB];
            bool okj[EB];
            #pragma unroll
            for (int j = 0; j < EB; j++) {
                int idx = e + 2 * j + half;
                okj[j] = idx < e1;
                sj[j] = okj[j] ? ssrc[idx] : 0;
            }
            #pragma unroll
            for (int j = 0; j < EB; j++)
                uj[j] = hsin[(size_t)sj[j] * 32 + fl];
            #pragma unroll
            for (int j = 0; j < EB; j++) {
                if (okj[j]) { ax += bflo(uj[j]); ay += bfhi(uj[j]); }
            }
        }
        ax += __shfl_xor(ax, 32);
        ay += __shfl_xor(ay, 32);
        uint32 su = hsin[(size_t)n * 32 + fl];
        ax += bflo(su);
        ay += bfhi(su);
        float dn = dinv[n];
        float2 h0v = *(const float2*)&h0[(size_t)n * HID + fl * 2];
        float ox = 0.9f * (dn * ax) + 0.1f * h0v.x;
        float oy = 0.9f * (dn * ay) + 0.1f * h0v.y;
        if (lane < 32) *(float2*)&ow[w][fl * 2] = make_float2(ox, oy);
        __builtin_amdgcn_wave_barrier();
        float acc2 = 0.f;
        #pragma unroll
        for (int f = 0; f < HID; f += 4) {
            float4 o4 = *(const float4*)&ow[w][f];
            acc2 = fmaf(o4.x, Ws[f + 0][lane], acc2);
            acc2 = fmaf(o4.y, Ws[f + 1][lane], acc2);
            acc2 = fmaf(o4.z, Ws[f + 2][lane], acc2);
            acc2 = fmaf(o4.w, Ws[f + 3][lane], acc2);
        }
        float oself = ow[w][lane];
        __builtin_amdgcn_wave_barrier();
        float hn = beta * acc2 + (1.f - beta) * oself;
        hsout[(size_t)n * HID + lane] = f2bf(dn * fmaxf(hn, 0.f));
    }
}

// ---------------- out = (hs/dinv) @ Wout + bout ----------------
__global__ __launch_bounds__(256) void k_final(const ushort16* __restrict__ hs,
                                               const float* __restrict__ dinv,
                                               const float* __restrict__ Wout,
                                               const float* __restrict__ bout,
                                               float* __restrict__ out) {
    int t = threadIdx.x;
    int w = t >> 6, lane = t & 63;
    int n = blockIdx.x * 4 + w;
    if (n >= N_NODES) return;
    float hv = bf2f(hs[(size_t)n * HID + lane]) * (1.0f / dinv[n]);
    #pragma unroll
    for (int c = 0; c < N_CLASSES; c++) {
        float p = hv * Wout[lane * N_CLASSES + c];
        #pragma unroll
        for (int off = 32; off > 0; off >>= 1) p += __shfl_xor(p, off);
        if (lane == 0) out[(size_t)n * N_CLASSES + c] = p + bout[c];
    }
}

extern "C" void kernel_launch(void* const* d_in, const int* in_sizes, int n_in,
                              void* d_out, int out_size, void* d_ws, size_t ws_size,
                              hipStream_t stream) {
    const float* x    = (const float*)d_in[0];
    const int*   ei   = (const int*)d_in[1];
    const float* W0   = (const float*)d_in[2];
    const float* b0   = (const float*)d_in[3];
    const float* Wl   = (const float*)d_in[4];
    const float* Wout = (const float*)d_in[5];
    const float* bout = (const float*)d_in[6];
    float* out = (float*)d_out;

    char* ws = (char*)d_ws;
    size_t off = 0;
    auto alloc = [&](size_t bytes) -> void* {
        void* p = ws + off;
        off += (bytes + 511) & ~(size_t)511;
        return p;
    };
    int*   flag  = (int*)alloc(4);
    int*   cnt   = (int*)alloc((size_t)N_NODES * 4);   // reused as `fill` after scan1
    float* dinv  = (float*)alloc((size_t)N_NODES * 4);
    int*   rs    = (int*)alloc((size_t)(N_NODES + 1) * 4);
    int*   bsum  = (int*)alloc(1024 * 4);
    int*   bofs  = (int*)alloc(1024 * 4);
    int*   ssrc  = (int*)alloc((size_t)N_EDGES * 4);
    float* h0    = (float*)alloc((size_t)N_NODES * HID * 4);
    void*  hsA   = alloc((size_t)N_NODES * HID * 2);   // bf16 state
    void*  hsB   = alloc((size_t)N_NODES * HID * 2);
    int* fill = cnt;  // alias: cnt is dead after k_scan1/k_dinv

    int nb_scan = CDIV(N_NODES, SCAN_ELEMS);  // 98

    k_detect<<<1, 64, 0, stream>>>((const unsigned int*)ei, flag);
    k_zero_cnt<<<CDIV(N_NODES, 256), 256, 0, stream>>>(cnt);
    k_count<<<CDIV(N_EDGES, 256), 256, 0, stream>>>(ei, flag, cnt);
    k_dinv<<<CDIV(N_NODES, 256), 256, 0, stream>>>(cnt, dinv);
    k_scan1<<<nb_scan, SCAN_T, 0, stream>>>(cnt, rs, bsum);
    k_scan2<<<1, 256, 0, stream>>>(bsum, bofs, nb_scan);
    k_scan3<<<CDIV(N_NODES, 256), 256, 0, stream>>>(rs, bofs, fill);
    k_scatter<<<CDIV(N_EDGES, 256), 256, 0, stream>>>(ei, flag, rs, fill, ssrc);

    k_h0<<<CDIV(N_NODES, 64), 256, 0, stream>>>(x, W0, b0, dinv, h0, (uint32*)hsA);

    // --- cooperative path: all 32 layers in one dispatch ---
    bool coop_done = false;
    {
        int maxb = 0;
        hipError_t qerr = hipOccupancyMaxActiveBlocksPerMultiprocessor(
            &maxb, (const void*)k_layers, 256, 0);
        if (qerr == hipSuccess && maxb > 0) {
            int grid = maxb * 256;  // 256 CUs on MI355X
            if (grid > 3125) grid = 3125;
            uint32* a0 = (uint32*)hsA;
            uint32* a1 = (uint32*)hsB;
            const float* h0p = h0;
            const float* wlp = Wl;
            const int* rsp = rs;
            const int* sp = ssrc;
            const float* dvp = dinv;
            void* args[] = { &a0, &a1, &h0p, &wlp, &rsp, &sp, &dvp };
            hipError_t lerr = hipLaunchCooperativeKernel(
                (void*)k_layers, dim3(grid), dim3(256), args, 0, stream);
            coop_done = (lerr == hipSuccess);
        }
    }

    const void* hin = hsA;
    if (!coop_done) {
        // fallback: classic per-layer launches (round-6 proven path)
        void* ho = hsB;
        for (int l = 0; l < LAYERS; l++) {
            float beta = logf(THETA / (float)(l + 1) + 1.0f);
            k_layer<<<N_NODES / NODES_PER_BLOCK, 256, 0, stream>>>(
                (const uint32*)hin, h0, (ushort16*)ho, Wl + (size_t)l * HID * HID,
                rs, ssrc, dinv, beta);
            hin = ho;
            ho = (hin == hsA) ? hsB : hsA;
        }
    }
    // LAYERS is even -> cooperative path also ends with result in hsA

    k_final<<<CDIV(N_NODES, 4), 256, 0, stream>>>((const ushort16*)hin, dinv, Wout, bout, out);
}

// Round 8
// 3089.355 us; speedup vs baseline: 2.2509x; 2.2509x over previous
//
#include <hip/hip_runtime.h>
#include <hip/hip_bf16.h>
#include <math.h>

#define N_NODES 100000
#define N_EDGES 3200000
#define IN_DIM 512
#define HID 64
#define N_CLASSES 7
#define LAYERS 32
#define ALPHA 0.1f
#define THETA 0.5f

#define CDIV(a, b) (((a) + (b) - 1) / (b))

typedef unsigned int uint32;
typedef unsigned short ushort16;

// bf16 helpers (RNE pack, bit-shift unpack)
__device__ __forceinline__ ushort16 f2bf(float f) {
    union { float f; uint32 u; } x; x.f = f;
    uint32 r = x.u + 0x7FFFu + ((x.u >> 16) & 1u);
    return (ushort16)(r >> 16);
}
__device__ __forceinline__ float bflo(uint32 u) {
    union { uint32 u; float f; } x; x.u = u << 16; return x.f;
}
__device__ __forceinline__ float bfhi(uint32 u) {
    union { uint32 u; float f; } x; x.u = u & 0xFFFF0000u; return x.f;
}
__device__ __forceinline__ float bf2f(ushort16 s) {
    union { uint32 u; float f; } x; x.u = ((uint32)s) << 16; return x.f;
}

// ---------------- edge dtype detection (int32 vs int64 storage) ----------------
__global__ void k_detect(const unsigned int* __restrict__ ei, int* __restrict__ flag) {
    if (threadIdx.x == 0 && blockIdx.x == 0) {
        int is64 = 1;
        for (int i = 0; i < 16; i++)
            if (ei[2 * i + 1] != 0u) { is64 = 0; break; }
        *flag = is64;
    }
}

__device__ __forceinline__ int edge_elem(const int* ei, int is64, int idx) {
    return is64 ? ei[2 * (long long)idx] : ei[idx];
}

// ---------------- degree histogram ----------------
__global__ void k_zero_cnt(int* __restrict__ cnt) {
    int i = blockIdx.x * blockDim.x + threadIdx.x;
    if (i < N_NODES) cnt[i] = 0;
}

__global__ void k_count(const int* __restrict__ ei, const int* __restrict__ flag,
                        int* __restrict__ cnt) {
    int is64 = *flag;
    int e = blockIdx.x * blockDim.x + threadIdx.x;
    if (e >= N_EDGES) return;
    int d = edge_elem(ei, is64, N_EDGES + e);
    atomicAdd(&cnt[d], 1);
}

__global__ void k_dinv(const int* __restrict__ cnt, float* __restrict__ dinv) {
    int i = blockIdx.x * blockDim.x + threadIdx.x;
    if (i < N_NODES) dinv[i] = rsqrtf((float)(cnt[i] + 1));  // +1 self-loop
}

// ---------------- exclusive scan over cnt -> row_start ----------------
#define SCAN_T 256
#define SCAN_ELEMS 1024

__global__ void k_scan1(const int* __restrict__ cnt, int* __restrict__ rs,
                        int* __restrict__ bsum) {
    __shared__ int sh[SCAN_T];
    int t = threadIdx.x;
    int base = blockIdx.x * SCAN_ELEMS + t * 4;
    int v0 = (base + 0 < N_NODES) ? cnt[base + 0] : 0;
    int v1 = (base + 1 < N_NODES) ? cnt[base + 1] : 0;
    int v2 = (base + 2 < N_NODES) ? cnt[base + 2] : 0;
    int v3 = (base + 3 < N_NODES) ? cnt[base + 3] : 0;
    int ts = v0 + v1 + v2 + v3;
    sh[t] = ts;
    __syncthreads();
    for (int off = 1; off < SCAN_T; off <<= 1) {
        int x = 0;
        if (t >= off) x = sh[t - off];
        __syncthreads();
        if (t >= off) sh[t] += x;
        __syncthreads();
    }
    int excl = sh[t] - ts;
    if (t == SCAN_T - 1) bsum[blockIdx.x] = sh[t];
    int run = excl;
    if (base + 0 < N_NODES) rs[base + 0] = run; run += v0;
    if (base + 1 < N_NODES) rs[base + 1] = run; run += v1;
    if (base + 2 < N_NODES) rs[base + 2] = run; run += v2;
    if (base + 3 < N_NODES) rs[base + 3] = run;
}

__global__ void k_scan2(const int* __restrict__ bsum, int* __restrict__ bofs, int nb) {
    __shared__ int sh[256];
    int t = threadIdx.x;
    int v = (t < nb) ? bsum[t] : 0;
    sh[t] = v;
    __syncthreads();
    for (int off = 1; off < 256; off <<= 1) {
        int x = 0;
        if (t >= off) x = sh[t - off];
        __syncthreads();
        if (t >= off) sh[t] += x;
        __syncthreads();
    }
    if (t < nb) bofs[t] = sh[t] - v;
}

__global__ void k_scan3(int* __restrict__ rs, const int* __restrict__ bofs,
                        int* __restrict__ fill) {
    int i = blockIdx.x * blockDim.x + threadIdx.x;
    if (i < N_NODES) {
        rs[i] += bofs[i / SCAN_ELEMS];
        fill[i] = 0;
    }
    if (i == 0) rs[N_NODES] = N_EDGES;
}

// ---------------- CSR scatter (sorted by dst) ----------------
__global__ void k_scatter(const int* __restrict__ ei, const int* __restrict__ flag,
                          const int* __restrict__ rs, int* __restrict__ fill,
                          int* __restrict__ ssrc) {
    int is64 = *flag;
    int e = blockIdx.x * blockDim.x + threadIdx.x;
    if (e >= N_EDGES) return;
    int s = edge_elem(ei, is64, e);
    int d = edge_elem(ei, is64, N_EDGES + e);
    int pos = rs[d] + atomicAdd(&fill[d], 1);
    ssrc[pos] = s;
}

// ---------------- h0 = relu(x @ W0 + b0) [f32]; hs0 = dinv*h0 [bf16x2] ----------------
__global__ __launch_bounds__(256) void k_h0(const float* __restrict__ x,
                                            const float* __restrict__ W0,
                                            const float* __restrict__ b0,
                                            const float* __restrict__ dinv,
                                            float* __restrict__ h0,
                                            uint32* __restrict__ hs0) {
    __shared__ float xs[32][68];
    __shared__ float ws[32][68];
    int t = threadIdx.x;
    int row0 = blockIdx.x * 64;
    int tm = t >> 4, tn = t & 15;
    float acc[4][4] = {};

    for (int k0 = 0; k0 < IN_DIM; k0 += 32) {
        #pragma unroll
        for (int j = 0; j < 2; j++) {
            int lin = t + j * 256;
            int r = lin >> 3, c4 = lin & 7;
            int row = row0 + r;
            float4 v = make_float4(0.f, 0.f, 0.f, 0.f);
            if (row < N_NODES)
                v = *(const float4*)&x[(size_t)row * IN_DIM + k0 + c4 * 4];
            xs[c4 * 4 + 0][r] = v.x;
            xs[c4 * 4 + 1][r] = v.y;
            xs[c4 * 4 + 2][r] = v.z;
            xs[c4 * 4 + 3][r] = v.w;
        }
        #pragma unroll
        for (int j = 0; j < 2; j++) {
            int lin = t + j * 256;
            int kr = lin >> 4, c4 = lin & 15;
            *(float4*)&ws[kr][c4 * 4] = *(const float4*)&W0[(size_t)(k0 + kr) * HID + c4 * 4];
        }
        __syncthreads();
        #pragma unroll
        for (int kk = 0; kk < 32; kk++) {
            float4 av = *(const float4*)&xs[kk][tm * 4];
            float4 bv = *(const float4*)&ws[kk][tn * 4];
            float a4[4] = {av.x, av.y, av.z, av.w};
            float b4[4] = {bv.x, bv.y, bv.z, bv.w};
            #pragma unroll
            for (int i = 0; i < 4; i++)
                #pragma unroll
                for (int j = 0; j < 4; j++)
                    acc[i][j] = fmaf(a4[i], b4[j], acc[i][j]);
        }
        __syncthreads();
    }
    #pragma unroll
    for (int i = 0; i < 4; i++) {
        int row = row0 + tm * 4 + i;
        if (row < N_NODES) {
            float dn = dinv[row];
            float4 o;
            o.x = fmaxf(acc[i][0] + b0[tn * 4 + 0], 0.f);
            o.y = fmaxf(acc[i][1] + b0[tn * 4 + 1], 0.f);
            o.z = fmaxf(acc[i][2] + b0[tn * 4 + 2], 0.f);
            o.w = fmaxf(acc[i][3] + b0[tn * 4 + 3], 0.f);
            *(float4*)&h0[(size_t)row * HID + tn * 4] = o;
            uint32 p0 = (uint32)f2bf(o.x * dn) | ((uint32)f2bf(o.y * dn) << 16);
            uint32 p1 = (uint32)f2bf(o.z * dn) | ((uint32)f2bf(o.w * dn) << 16);
            uint2 pk; pk.x = p0; pk.y = p1;
            *(uint2*)&hs0[(size_t)row * 32 + tn * 2] = pk;
        }
    }
}

// ---------------- one GCN2 layer: 16-lane groups, reg-resident indices ----------------
// wave = 4 groups x 16 lanes; group g owns node n = blk*16 + w*4 + g.
// Lane sl in group reads features [4sl..4sl+3] (one uint2 = 8B of the 128B row).
// Edge indices for a 32-edge block live in 2 regs/lane, distributed via shfl;
// all gathers within a block are memory-dependency-free.
#define EW 8  // gather instructions per window (x4 rows each = 32 edges in flight/wave)
__global__ __launch_bounds__(256) void k_layer(
    const uint32* __restrict__ hsin, const float* __restrict__ h0,
    ushort16* __restrict__ hsout, const float* __restrict__ W,
    const int* __restrict__ rs, const int* __restrict__ ssrc,
    const float* __restrict__ dinv, float beta) {
    __shared__ float Ws[HID][HID + 1];
    __shared__ float ow[4][4][HID];  // [wave][group][feat]
    int t = threadIdx.x;
    #pragma unroll
    for (int j = 0; j < 16; j++) {
        int lin = t + j * 256;
        Ws[lin >> 6][lin & 63] = W[lin];
    }
    __syncthreads();

    int w = t >> 6, lane = t & 63;
    int g = lane >> 4, sl = lane & 15;
    int gbase = lane & 48;            // g*16, shfl group base
    int nbase = blockIdx.x * 16 + w * 4;
    int n = nbase + g;                // N_NODES = 6250*16 -> always in range

    int e0 = rs[n], e1 = rs[n + 1];
    int last = max(e1 - 1, e0);       // clamp target (safe even for deg==0)
    int nblk = (e1 - e0 + 31) >> 5;   // 32-edge blocks for this node
    // wave-uniform max block count
    int m = nblk;
    m = max(m, __shfl_xor(m, 16));
    m = max(m, __shfl_xor(m, 32));

    float a0 = 0.f, a1 = 0.f, a2 = 0.f, a3 = 0.f;
    const uint2* hs2 = (const uint2*)hsin;

    // preload first 32 indices (2 coalesced loads per group)
    int ia = ssrc[min(e0 + sl, last)];
    int ib = ssrc[min(e0 + 16 + sl, last)];

    #pragma unroll 1
    for (int b = 0; b < m; b++) {
        int ebase = e0 + (b << 5);
        // prefetch next block's indices while this block's gathers run
        int na = ia, nb2 = ib;
        if (b + 1 < m) {
            na  = ssrc[min(ebase + 32 + sl, last)];
            nb2 = ssrc[min(ebase + 48 + sl, last)];
        }
        #pragma unroll 1
        for (int jw = 0; jw < 32; jw += EW) {
            uint2 u[EW];
            #pragma unroll
            for (int j = 0; j < EW; j++) {
                int jj = jw + j;
                int idx = __shfl((jj < 16) ? ia : ib, gbase + (jj & 15));
                u[j] = hs2[(size_t)idx * 16 + sl];
            }
            #pragma unroll
            for (int j = 0; j < EW; j++) {
                if (ebase + jw + j < e1) {
                    a0 += bflo(u[j].x); a1 += bfhi(u[j].x);
                    a2 += bflo(u[j].y); a3 += bfhi(u[j].y);
                }
            }
        }
        ia = na; ib = nb2;
    }

    // self-loop term
    uint2 su = hs2[(size_t)n * 16 + sl];
    a0 += bflo(su.x); a1 += bfhi(su.x);
    a2 += bflo(su.y); a3 += bfhi(su.y);

    float dn = dinv[n];
    float4 h0v = *(const float4*)&h0[(size_t)n * HID + 4 * sl];
    float o0 = 0.9f * (dn * a0) + 0.1f * h0v.x;
    float o1 = 0.9f * (dn * a1) + 0.1f * h0v.y;
    float o2 = 0.9f * (dn * a2) + 0.1f * h0v.z;
    float o3 = 0.9f * (dn * a3) + 0.1f * h0v.w;
    *(float4*)&ow[w][g][4 * sl] = make_float4(o0, o1, o2, o3);
    __builtin_amdgcn_wave_barrier();  // DS writes before DS reads (in-order per wave)

    // 64x64 GEMM + identity mix + relu for the wave's 4 nodes, lane = output feature
    #pragma unroll
    for (int gn = 0; gn < 4; gn++) {
        float acc2 = 0.f;
        #pragma unroll
        for (int f = 0; f < HID; f += 4) {
            float4 o4 = *(const float4*)&ow[w][gn][f];  // wave-broadcast
            acc2 = fmaf(o4.x, Ws[f + 0][lane], acc2);
            acc2 = fmaf(o4.y, Ws[f + 1][lane], acc2);
            acc2 = fmaf(o4.z, Ws[f + 2][lane], acc2);
            acc2 = fmaf(o4.w, Ws[f + 3][lane], acc2);
        }
        float oself = ow[w][gn][lane];
        float hn = beta * acc2 + (1.f - beta) * oself;
        int nn = nbase + gn;
        hsout[(size_t)nn * HID + lane] = f2bf(dinv[nn] * fmaxf(hn, 0.f));
    }
}

// ---------------- out = (hs/dinv) @ Wout + bout ----------------
__global__ __launch_bounds__(256) void k_final(const ushort16* __restrict__ hs,
                                               const float* __restrict__ dinv,
                                               const float* __restrict__ Wout,
                                               const float* __restrict__ bout,
                                               float* __restrict__ out) {
    int t = threadIdx.x;
    int w = t >> 6, lane = t & 63;
    int n = blockIdx.x * 4 + w;
    if (n >= N_NODES) return;
    float hv = bf2f(hs[(size_t)n * HID + lane]) * (1.0f / dinv[n]);
    #pragma unroll
    for (int c = 0; c < N_CLASSES; c++) {
        float p = hv * Wout[lane * N_CLASSES + c];
        #pragma unroll
        for (int off = 32; off > 0; off >>= 1) p += __shfl_xor(p, off);
        if (lane == 0) out[(size_t)n * N_CLASSES + c] = p + bout[c];
    }
}

extern "C" void kernel_launch(void* const* d_in, const int* in_sizes, int n_in,
                              void* d_out, int out_size, void* d_ws, size_t ws_size,
                              hipStream_t stream) {
    const float* x    = (const float*)d_in[0];
    const int*   ei   = (const int*)d_in[1];
    const float* W0   = (const float*)d_in[2];
    const float* b0   = (const float*)d_in[3];
    const float* Wl   = (const float*)d_in[4];
    const float* Wout = (const float*)d_in[5];
    const float* bout = (const float*)d_in[6];
    float* out = (float*)d_out;

    char* ws = (char*)d_ws;
    size_t off = 0;
    auto alloc = [&](size_t bytes) -> void* {
        void* p = ws + off;
        off += (bytes + 511) & ~(size_t)511;
        return p;
    };
    int*   flag  = (int*)alloc(4);
    int*   cnt   = (int*)alloc((size_t)N_NODES * 4);   // reused as `fill` after scan1
    float* dinv  = (float*)alloc((size_t)N_NODES * 4);
    int*   rs    = (int*)alloc((size_t)(N_NODES + 1) * 4);
    int*   bsum  = (int*)alloc(1024 * 4);
    int*   bofs  = (int*)alloc(1024 * 4);
    int*   ssrc  = (int*)alloc((size_t)(N_EDGES + 64) * 4);  // +64 pad for clamped prefetch
    float* h0    = (float*)alloc((size_t)N_NODES * HID * 4);
    void*  hsA   = alloc((size_t)N_NODES * HID * 2);   // bf16 state
    void*  hsB   = alloc((size_t)N_NODES * HID * 2);
    int* fill = cnt;  // alias: cnt is dead after k_scan1/k_dinv

    int nb_scan = CDIV(N_NODES, SCAN_ELEMS);  // 98

    k_detect<<<1, 64, 0, stream>>>((const unsigned int*)ei, flag);
    k_zero_cnt<<<CDIV(N_NODES, 256), 256, 0, stream>>>(cnt);
    k_count<<<CDIV(N_EDGES, 256), 256, 0, stream>>>(ei, flag, cnt);
    k_dinv<<<CDIV(N_NODES, 256), 256, 0, stream>>>(cnt, dinv);
    k_scan1<<<nb_scan, SCAN_T, 0, stream>>>(cnt, rs, bsum);
    k_scan2<<<1, 256, 0, stream>>>(bsum, bofs, nb_scan);
    k_scan3<<<CDIV(N_NODES, 256), 256, 0, stream>>>(rs, bofs, fill);
    k_scatter<<<CDIV(N_EDGES, 256), 256, 0, stream>>>(ei, flag, rs, fill, ssrc);

    k_h0<<<CDIV(N_NODES, 64), 256, 0, stream>>>(x, W0, b0, dinv, h0, (uint32*)hsA);

    const void* hin = hsA;
    void* ho = hsB;
    for (int l = 0; l < LAYERS; l++) {
        float beta = logf(THETA / (float)(l + 1) + 1.0f);
        k_layer<<<N_NODES / 16, 256, 0, stream>>>(
            (const uint32*)hin, h0, (ushort16*)ho, Wl + (size_t)l * HID * HID,
            rs, ssrc, dinv, beta);
        hin = ho;
        ho = (hin == hsA) ? hsB : hsA;
    }

    k_final<<<CDIV(N_NODES, 4), 256, 0, stream>>>((const ushort16*)hin, dinv, Wout, bout, out);
}